// Round 2
// baseline (88.516 us; speedup 1.0000x reference)
//
#include <hip/hip_runtime.h>
#include <math.h>

#define NB 16      // batches
#define NN 1024    // visual tokens
#define ND 768     // feature dim
#define NT 256     // text tokens
#define NSEL 16    // selections
#define NC 64      // greedy candidate set (global top-64 by initial di2s)

typedef __attribute__((ext_vector_type(8))) short short8;
typedef __attribute__((ext_vector_type(4))) float f32x4;
typedef __attribute__((ext_vector_type(8))) unsigned short ushort8v;
typedef unsigned long long u64;

// ---- device scratch (every read dominated by a same-launch write) ----
__device__ __align__(16) float g_invv[NB*NN];
__device__ __align__(16) float g_diagv[NB*NN];
__device__ __align__(16) float g_mrawp[NB*NN*2];  // per-128-text-half rowmax
// fragment-order pre-split text: unit(b,th,s,h,ct,lane) of 16B (8 bf16); s = 32-k step
__device__ __align__(16) ushort8v g_tf[NB*2*24*2*8*64];

__device__ __forceinline__ unsigned short f2bf(float x) {
    unsigned u = __float_as_uint(x);
    return (unsigned short)((u + 0x7FFFu + ((u >> 16) & 1u)) >> 16);
}
__device__ __forceinline__ float bf2f(unsigned short h) {
    return __uint_as_float(((unsigned)h) << 16);
}
__device__ __forceinline__ size_t tfidx(int b, int th, int s, int h, int ct, int lane) {
    return ((((size_t)(b*2 + th)*24 + s)*2 + h)*8 + ct)*64 + lane;
}

// ---------------- K1: text norms + bf16 hi/lo split -> FRAGMENT-ORDER global ----------------
__global__ __launch_bounds__(256) void ktxt(const float* __restrict__ txt) {
    int gw = (blockIdx.x * 256 + threadIdx.x) >> 6;   // row 0..NB*NT-1
    int l  = threadIdx.x & 63;
    int b  = gw >> 8, r = gw & 255;
    int th = r >> 7, ct = (r >> 4) & 7, rlo = r & 15;
    const float* row = txt + (size_t)gw * ND;

    float4 x0 = *(const float4*)(row + 8*l);
    float4 y0 = *(const float4*)(row + 8*l + 4);
    float4 x1 = {0,0,0,0}, y1 = {0,0,0,0};
    bool two = (l < 32);
    if (two) {
        x1 = *(const float4*)(row + 512 + 8*l);
        y1 = *(const float4*)(row + 512 + 8*l + 4);
    }
    float s = x0.x*x0.x + x0.y*x0.y + x0.z*x0.z + x0.w*x0.w
            + y0.x*y0.x + y0.y*y0.y + y0.z*y0.z + y0.w*y0.w;
    if (two) s += x1.x*x1.x + x1.y*x1.y + x1.z*x1.z + x1.w*x1.w
                + y1.x*y1.x + y1.y*y1.y + y1.z*y1.z + y1.w*y1.w;
    #pragma unroll
    for (int off = 32; off; off >>= 1) s += __shfl_xor(s, off);
    float inv = 1.0f / (sqrtf(s) + 1e-6f);

    int kslot = l & 3;
    int lane  = kslot*16 + rlo;
    {   // chunk 0: e0 = 8l, s-step = l>>2
        int st = l >> 2;
        float a[8] = {x0.x, x0.y, x0.z, x0.w, y0.x, y0.y, y0.z, y0.w};
        ushort8v hh, ll;
        #pragma unroll
        for (int j = 0; j < 8; j++) {
            float v = a[j] * inv;
            hh[j] = f2bf(v);
            ll[j] = f2bf(v - bf2f(hh[j]));
        }
        g_tf[tfidx(b, th, st, 0, ct, lane)] = hh;
        g_tf[tfidx(b, th, st, 1, ct, lane)] = ll;
    }
    if (two) {  // chunk 1: e0 = 512+8l, s-step = 16 + (l>>2)
        int st = 16 + (l >> 2);
        float a[8] = {x1.x, x1.y, x1.z, x1.w, y1.x, y1.y, y1.z, y1.w};
        ushort8v hh, ll;
        #pragma unroll
        for (int j = 0; j < 8; j++) {
            float v = a[j] * inv;
            hh[j] = f2bf(v);
            ll[j] = f2bf(v - bf2f(hh[j]));
        }
        g_tf[tfidx(b, th, st, 0, ct, lane)] = hh;
        g_tf[tfidx(b, th, st, 1, ct, lane)] = ll;
    }
}

// ---------------- K2 v3: r20 LDS structure + 32 rows/wave (2 A-frags) ----------------
// Post-mortem v2: global-B path was latency-bound at 1 wave/SIMD (MfmaUtil*dur invariant
// proved pure scheduling loss). Revert to the PROVEN r20 triple-buffer global_load_lds
// structure; single structural change: each wave computes 32 rows (2 M-frags) so the
// per-step 16KB B-tile ds_read amortizes over 2x output. Blocks shrink to 128 threads
// (2 waves), grid 512 -> still 2 blocks/CU: per CU/step LDS 768 cyc < MFMA 1242 cyc
// (was 1536 vs 1242 = LDS-bound). Barriers now sync only 2 waves; the two independent
// blocks/CU stagger to cover each other's barrier drain. T5 setprio around MFMA cluster
// (2-block stagger = role diversity). MFMA order per output element unchanged ->
// bit-identical relevance/invv/diag vs r20.
// XCD swizzle: lid = (bid&7)*64 + bid>>3 (bijective, 512 = 8x64) -> each XCD owns
// 2 full batches (both th, all row-blocks): 1.5MB g_tf L2-resident, th-pairs co-XCD.
__global__ __launch_bounds__(128, 1) void krel(const float* __restrict__ vis) {
    int bid = blockIdx.x;
    int lid = (bid & 7) * 64 + (bid >> 3);   // XCD-grouped logical id
    int b   = lid >> 5;
    int r   = lid & 31;
    int th  = r & 1;
    int blk = r >> 1;                         // 0..15: 64-row block within (b,th)
    int t   = threadIdx.x;
    int w   = t >> 6, l = t & 63;

    __shared__ __align__(16) ushort8v Bfrag[3][2][8][64];  // [buf][hi/lo][ct][lane], 48KB

    f32x4 acc0[8], acc1[8];
    #pragma unroll
    for (int ct = 0; ct < 8; ct++) {
        acc0[ct] = (f32x4){0.f, 0.f, 0.f, 0.f};
        acc1[ct] = (f32x4){0.f, 0.f, 0.f, 0.f};
    }

    int base = blk*64 + w*32;                 // first of this wave's 32 rows
    // A fragments: frag m covers rows base + m*16 + (l&15), k-slot (l>>4)*8
    const float* Ap0 = vis + ((size_t)(b*NN + base + (l & 15)))*ND + (l >> 4)*8;
    const float* Ap1 = Ap0 + (size_t)16*ND;

    // B staging: wave w issues chunks c = w*8..w*8+7; c -> (h = c>>3, ct = c&7)
    const ushort8v* Bbase = g_tf + (size_t)(b*2 + th)*(24*2*8*64);

    #define STAGE(S, P)                                                          \
        {                                                                        \
            _Pragma("unroll")                                                    \
            for (int q = 0; q < 8; q++) {                                        \
                int c  = w*8 + q;                                                \
                int h  = c >> 3, ct = c & 7;                                     \
                const ushort8v* gsrc = Bbase + (((size_t)(S)*2 + h)*8 + ct)*64 + l; \
                __builtin_amdgcn_global_load_lds(                                \
                    (const __attribute__((address_space(1))) void*)gsrc,         \
                    (__attribute__((address_space(3))) void*)&Bfrag[P][h][ct][0],\
                    16, 0, 0);                                                   \
            }                                                                    \
        }

    // prologue: A regs for step 0; B tiles 0 and 1 into buf 0,1; full drain once
    float4 a0x = *(const float4*)(Ap0);
    float4 a0y = *(const float4*)(Ap0 + 4);
    float4 a1x = *(const float4*)(Ap1);
    float4 a1y = *(const float4*)(Ap1 + 4);
    STAGE(0, 0);
    STAGE(1, 1);
    __syncthreads();
    float ss0 = 0.f, ss1 = 0.f;

    for (int s = 0; s < 24; s++) {
        int p = s % 3;
        // issue step-(s+2) B loads (2 steps ahead; in flight across the next barrier)
        if (s < 22) STAGE(s + 2, (s + 2) % 3);
        asm volatile("" ::: "memory");   // keep STAGE issued before the A-wait below
        // convert A regs -> hi/lo fragments + sumsq (same per-element order as r20)
        short8 ah0, al0, ah1, al1;
        {
            float av[8] = {a0x.x, a0x.y, a0x.z, a0x.w, a0y.x, a0y.y, a0y.z, a0y.w};
            ushort8v hh, ll;
            #pragma unroll
            for (int j = 0; j < 8; j++) {
                hh[j] = f2bf(av[j]);
                ll[j] = f2bf(av[j] - bf2f(hh[j]));
                ss0 = fmaf(av[j], av[j], ss0);
            }
            ah0 = *(short8*)&hh; al0 = *(short8*)&ll;
        }
        {
            float av[8] = {a1x.x, a1x.y, a1x.z, a1x.w, a1y.x, a1y.y, a1y.z, a1y.w};
            ushort8v hh, ll;
            #pragma unroll
            for (int j = 0; j < 8; j++) {
                hh[j] = f2bf(av[j]);
                ll[j] = f2bf(av[j] - bf2f(hh[j]));
                ss1 = fmaf(av[j], av[j], ss1);
            }
            ah1 = *(short8*)&hh; al1 = *(short8*)&ll;
        }
        // prefetch next A regs (issued after this step's STAGE -> the compiler's wait
        // on these before next step's conv drains STAGE(s+2); overlaps MFMA below)
        if (s < 23) {
            int k1 = (s + 1) * 32;
            a0x = *(const float4*)(Ap0 + k1);
            a0y = *(const float4*)(Ap0 + k1 + 4);
            a1x = *(const float4*)(Ap1 + k1);
            a1y = *(const float4*)(Ap1 + k1 + 4);
        }
        // MFMA: 8 col-tiles; per (frag, ct) pass order hh, lh, hl, ll -> bit-identical
        __builtin_amdgcn_s_setprio(1);
        #pragma unroll
        for (int ct = 0; ct < 8; ct++) {
            short8 bh = *(const short8*)&Bfrag[p][0][ct][l];
            short8 bl = *(const short8*)&Bfrag[p][1][ct][l];
            acc0[ct] = __builtin_amdgcn_mfma_f32_16x16x32_bf16(ah0, bh, acc0[ct], 0, 0, 0);
            acc0[ct] = __builtin_amdgcn_mfma_f32_16x16x32_bf16(al0, bh, acc0[ct], 0, 0, 0);
            acc0[ct] = __builtin_amdgcn_mfma_f32_16x16x32_bf16(ah0, bl, acc0[ct], 0, 0, 0);
            acc0[ct] = __builtin_amdgcn_mfma_f32_16x16x32_bf16(al0, bl, acc0[ct], 0, 0, 0);
            acc1[ct] = __builtin_amdgcn_mfma_f32_16x16x32_bf16(ah1, bh, acc1[ct], 0, 0, 0);
            acc1[ct] = __builtin_amdgcn_mfma_f32_16x16x32_bf16(al1, bh, acc1[ct], 0, 0, 0);
            acc1[ct] = __builtin_amdgcn_mfma_f32_16x16x32_bf16(ah1, bl, acc1[ct], 0, 0, 0);
            acc1[ct] = __builtin_amdgcn_mfma_f32_16x16x32_bf16(al1, bl, acc1[ct], 0, 0, 0);
        }
        __builtin_amdgcn_s_setprio(0);
        if (s < 23) {
            // exec-sync only: staging for step s+1 already drained by this step's
            // A-wait (in-order vmcnt); no vmcnt(0) -> 2-steps-ahead loads stay in flight
            asm volatile("s_waitcnt lgkmcnt(0)" ::: "memory");
            __builtin_amdgcn_s_barrier();
            __builtin_amdgcn_sched_barrier(0);
        }
    }
    #undef STAGE

    // rowmax over this half's 128 cols (exact; kfinal maxes the 2 halves) + invv/diag
    #define EPI(ACC, MOFF, SS)                                                 \
        {                                                                      \
            _Pragma("unroll")                                                  \
            for (int rr = 0; rr < 4; rr++) {                                   \
                float mx_ = ACC[0][rr];                                        \
                _Pragma("unroll")                                              \
                for (int ct = 1; ct < 8; ct++) mx_ = fmaxf(mx_, ACC[ct][rr]);  \
                _Pragma("unroll")                                              \
                for (int off = 1; off <= 8; off <<= 1)                         \
                    mx_ = fmaxf(mx_, __shfl_xor(mx_, off));                    \
                if ((l & 15) == 0)                                             \
                    g_mrawp[(size_t)(b*NN + base + (MOFF) + (l >> 4)*4 + rr)*2 + th] = mx_; \
            }                                                                  \
            float sst_ = SS;                                                   \
            sst_ += __shfl_xor(sst_, 16);                                      \
            sst_ += __shfl_xor(sst_, 32);                                      \
            if (th == 0 && l < 16) {                                           \
                int row_ = base + (MOFF) + l;                                  \
                float nrm_ = sqrtf(sst_);                                      \
                float inv_ = 1.0f / (nrm_ + 1e-6f);                            \
                g_invv[b*NN + row_] = inv_;                                    \
                float dd_ = nrm_ * inv_;                                       \
                g_diagv[b*NN + row_] = dd_ * dd_;                              \
            }                                                                  \
        }
    EPI(acc0, 0,  ss0)
    EPI(acc1, 16, ss1)
    #undef EPI
}

// ---------------- K3: prep + reg-sort top-64 + MFMA Gram + single-wave greedy + gather ----------------
__global__ __launch_bounds__(1024) void kfinal(const float* __restrict__ vis,
                                               float* __restrict__ out) {
    int b = blockIdx.x;
    int t = threadIdx.x;
    int w = t >> 6, l = t & 63;

    __shared__ u64   s_key[NN];
    __shared__ float s_reln[NN];
    __shared__ __align__(16) unsigned short Chi[NC][392], Clo[NC][392];  // K-chunk 384 + pad
    __shared__ float s_S[NC*65];
    __shared__ int   s_sel[NSEL], s_srt[NSEL];
    __shared__ float s_mn[16], s_mx[16], s_b2[2];

    // ---- prep: relevance minmax-normalize, di2s0, key (1 elem/thread) ----
    float m0 = g_mrawp[(size_t)(b*NN + t)*2 + 0];
    float m1 = g_mrawp[(size_t)(b*NN + t)*2 + 1];
    float iv = g_invv[b*NN + t], dd = g_diagv[b*NN + t];
    float rr = fmaxf(m0, m1) * iv;
    float lmin = rr, lmax = rr;
    #pragma unroll
    for (int off = 32; off; off >>= 1) {
        lmin = fminf(lmin, __shfl_xor(lmin, off));
        lmax = fmaxf(lmax, __shfl_xor(lmax, off));
    }
    if (l == 0) { s_mn[w] = lmin; s_mx[w] = lmax; }
    __syncthreads();
    if (t == 0) {
        float mn = s_mn[0], mx = s_mx[0];
        #pragma unroll
        for (int q = 1; q < 16; q++) { mn = fminf(mn, s_mn[q]); mx = fmaxf(mx, s_mx[q]); }
        s_b2[0] = mn; s_b2[1] = mx;
    }
    __syncthreads();
    float mn = s_b2[0], mx = s_b2[1];
    float den = mx - mn + 1e-6f;
    float rn = (rr - mn + 1e-6f) / den;
    float d0 = rn * rn * dd;
    s_reln[t] = rn;
    u64 kreg = ((u64)(~__float_as_uint(d0)) << 10) | (unsigned)t;

    // ---- per-wave in-register bitonic sort (ascending key = descending d0) ----
    #pragma unroll
    for (int k = 2; k <= 64; k <<= 1) {
        #pragma unroll
        for (int j = k >> 1; j > 0; j >>= 1) {
            u64 part = __shfl_xor(kreg, j);
            bool takeMin = ((l & k) == 0) == ((l & j) == 0);
            kreg = takeMin ? (kreg < part ? kreg : part) : (kreg < part ? part : kreg);
        }
    }
    // ---- symmetric tournament merge: 4 rounds, every wave ends with global top-64 ----
    #pragma unroll
    for (int rnd = 0; rnd < 4; rnd++) {
        int dstp = 8 >> rnd;
        s_key[w*64 + l] = kreg;
        __syncthreads();
        u64 other = s_key[(w ^ dstp)*64 + (63 - l)];
        u64 m = (kreg < other) ? kreg : other;     // 64 smallest of union (bitonic)
        #pragma unroll
        for (int j = 32; j > 0; j >>= 1) {         // ascending clean
            u64 part = __shfl_xor(m, j);
            bool takeMin = ((l & j) == 0);
            m = takeMin ? (m < part ? m : part) : (m < part ? part : m);
        }
        kreg = m;
        __syncthreads();
    }

    // lane l of every wave: l-th best candidate
    int   gid = (int)(kreg & 1023u);
    float d0v = __uint_as_float(~(unsigned)(kreg >> 10));

    // ---- Gram S = vn_c . vn_c^T via bf16x4 MFMA, 2 chunks of K=384 ----
    f32x4 acc = (f32x4){0.f, 0.f, 0.f, 0.f};
    int ar0 = (w >> 2) * 16, bc0 = (w & 3) * 16;
    int cr  = (w << 2) + (l >> 4);                 // candidate row this thread stages
    int sgid = __shfl(gid, cr);
    float sc = g_invv[b*NN + sgid];
    const float* srcrow = vis + (size_t)(b*NN + sgid)*ND + (l & 15)*24;

    for (int c = 0; c < 2; c++) {
        __syncthreads();
        int kb = (l & 15) * 24;
        #pragma unroll
        for (int q = 0; q < 3; q++) {
            float4 x = *(const float4*)(srcrow + c*384 + q*8);
            float4 y = *(const float4*)(srcrow + c*384 + q*8 + 4);
            float av[8] = {x.x, x.y, x.z, x.w, y.x, y.y, y.z, y.w};
            ushort8v hh, ll;
            #pragma unroll
            for (int j = 0; j < 8; j++) {
                float vv = av[j] * sc;
                hh[j] = f2bf(vv);
                ll[j] = f2bf(vv - bf2f(hh[j]));
            }
            *(ushort8v*)&Chi[cr][kb + q*8] = hh;
            *(ushort8v*)&Clo[cr][kb + q*8] = ll;
        }
        __syncthreads();
        #pragma unroll
        for (int ks = 0; ks < 12; ks++) {
            int ko = ks*32 + (l >> 4)*8;
            short8 ah = *(const short8*)&Chi[ar0 + (l & 15)][ko];
            short8 al = *(const short8*)&Clo[ar0 + (l & 15)][ko];
            short8 bh = *(const short8*)&Chi[bc0 + (l & 15)][ko];
            short8 bl = *(const short8*)&Clo[bc0 + (l & 15)][ko];
            acc = __builtin_amdgcn_mfma_f32_16x16x32_bf16(ah, bh, acc, 0, 0, 0);
            acc = __builtin_amdgcn_mfma_f32_16x16x32_bf16(al, bh, acc, 0, 0, 0);
            acc = __builtin_amdgcn_mfma_f32_16x16x32_bf16(ah, bl, acc, 0, 0, 0);
            acc = __builtin_amdgcn_mfma_f32_16x16x32_bf16(al, bl, acc, 0, 0, 0);
        }
    }
    #pragma unroll
    for (int r = 0; r < 4; r++)
        s_S[(ar0 + (l >> 4)*4 + r)*65 + bc0 + (l & 15)] = acc[r];
    __syncthreads();

    // ---- single-wave greedy: lane = candidate, zero barriers, all state in registers ----
    if (w == 0) {
        float di  = d0v;
        int   gd  = gid;
        float rel = s_reln[gid];
        float ownc[NSEL];
        #pragma unroll
        for (int i = 0; i < NSEL; i++) {
            float vq = fmaxf(di, 1e-12f);
            int   gq = gd;
            int   cq = l;
            #pragma unroll
            for (int off = 32; off; off >>= 1) {
                float vo = __shfl_xor(vq, off);
                int   go = __shfl_xor(gq, off);
                int   co = __shfl_xor(cq, off);
                if (vo > vq || (vo == vq && go < gq)) { vq = vo; gq = go; cq = co; }
            }
            float dj   = __shfl(di, cq);
            float relj = __shfl(rel, cq);
            float denom = sqrtf(fmaxf(dj, 1e-12f)) + 1e-8f;
            if (l == 0) s_sel[i] = gq;

            float cov = 0.f;
            #pragma unroll
            for (int q = 0; q < i; q++)
                cov = fmaf(ownc[q], __shfl(ownc[q], cq), cov);

            float sim = s_S[l*65 + cq];
            float kj  = rel * relj * sim;
            float eis = (kj - cov) / denom;
            ownc[i] = eis;
            di = di - eis * eis;
            if (l == cq) di = -__builtin_inff();
        }
    }
    __syncthreads();

    // ---- sort selected indices; wave w gathers output row w ----
    if (t == 0) {
        int vv[16];
        #pragma unroll
        for (int q = 0; q < 16; q++) vv[q] = s_sel[q];
        for (int a = 1; a < 16; a++) {
            int key = vv[a]; int p2 = a - 1;
            while (p2 >= 0 && vv[p2] > key) { vv[p2+1] = vv[p2]; p2--; }
            vv[p2+1] = key;
        }
        #pragma unroll
        for (int q = 0; q < 16; q++) s_srt[q] = vv[q];
    }
    __syncthreads();
    {
        int idx = s_srt[w];
        const float* src = vis + (size_t)(b*NN + idx)*ND + l*12;
        float*       dst = out + (size_t)(b*NSEL + w)*ND + l*12;
        float4 x = *(const float4*)(src);
        float4 y = *(const float4*)(src + 4);
        float4 z = *(const float4*)(src + 8);
        *(float4*)(dst)     = x;
        *(float4*)(dst + 4) = y;
        *(float4*)(dst + 8) = z;
    }
}

extern "C" void kernel_launch(void* const* d_in, const int* in_sizes, int n_in,
                              void* d_out, int out_size, void* d_ws, size_t ws_size,
                              hipStream_t stream) {
    (void)in_sizes; (void)n_in; (void)d_ws; (void)ws_size; (void)out_size;
    const float* vis = (const float*)d_in[0];
    const float* txt = (const float*)d_in[1];
    float* out = (float*)d_out;

    ktxt  <<<dim3((NB*NT)/4), dim3(256),  0, stream>>>(txt);
    krel  <<<dim3(512),       dim3(128),  0, stream>>>(vis);
    kfinal<<<dim3(NB),        dim3(1024), 0, stream>>>(vis, out);
}

// Round 3
// 75.945 us; speedup vs baseline: 1.1655x; 1.1655x over previous
//
#include <hip/hip_runtime.h>
#include <math.h>

#define NB 16      // batches
#define NN 1024    // visual tokens
#define ND 768     // feature dim
#define NT 256     // text tokens
#define NSEL 16    // selections
#define NC 64      // greedy candidate set (global top-64 by initial di2s)

typedef __attribute__((ext_vector_type(8))) short short8;
typedef __attribute__((ext_vector_type(4))) float f32x4;
typedef __attribute__((ext_vector_type(8))) unsigned short ushort8v;
typedef unsigned long long u64;

// ---- device scratch (every read dominated by a same-launch write) ----
__device__ __align__(16) float g_invv[NB*NN];
__device__ __align__(16) float g_diagv[NB*NN];
__device__ __align__(16) float g_mrawp[NB*NN*4];  // per-64-text-quarter rowmax
// fragment-order pre-split text: unit(b,th,s,h,ct,lane) of 16B (8 bf16); s = 32-k step
__device__ __align__(16) ushort8v g_tf[NB*2*24*2*8*64];

__device__ __forceinline__ unsigned short f2bf(float x) {
    unsigned u = __float_as_uint(x);
    return (unsigned short)((u + 0x7FFFu + ((u >> 16) & 1u)) >> 16);
}
__device__ __forceinline__ float bf2f(unsigned short h) {
    return __uint_as_float(((unsigned)h) << 16);
}
__device__ __forceinline__ size_t tfidx(int b, int th, int s, int h, int ct, int lane) {
    return ((((size_t)(b*2 + th)*24 + s)*2 + h)*8 + ct)*64 + lane;
}

// ---------------- K1: text norms + bf16 hi/lo split -> FRAGMENT-ORDER global ----------------
__global__ __launch_bounds__(256) void ktxt(const float* __restrict__ txt) {
    int gw = (blockIdx.x * 256 + threadIdx.x) >> 6;   // row 0..NB*NT-1
    int l  = threadIdx.x & 63;
    int b  = gw >> 8, r = gw & 255;
    int th = r >> 7, ct = (r >> 4) & 7, rlo = r & 15;
    const float* row = txt + (size_t)gw * ND;

    float4 x0 = *(const float4*)(row + 8*l);
    float4 y0 = *(const float4*)(row + 8*l + 4);
    float4 x1 = {0,0,0,0}, y1 = {0,0,0,0};
    bool two = (l < 32);
    if (two) {
        x1 = *(const float4*)(row + 512 + 8*l);
        y1 = *(const float4*)(row + 512 + 8*l + 4);
    }
    float s = x0.x*x0.x + x0.y*x0.y + x0.z*x0.z + x0.w*x0.w
            + y0.x*y0.x + y0.y*y0.y + y0.z*y0.z + y0.w*y0.w;
    if (two) s += x1.x*x1.x + x1.y*x1.y + x1.z*x1.z + x1.w*x1.w
                + y1.x*y1.x + y1.y*y1.y + y1.z*y1.z + y1.w*y1.w;
    #pragma unroll
    for (int off = 32; off; off >>= 1) s += __shfl_xor(s, off);
    float inv = 1.0f / (sqrtf(s) + 1e-6f);

    int kslot = l & 3;
    int lane  = kslot*16 + rlo;
    {   // chunk 0: e0 = 8l, s-step = l>>2
        int st = l >> 2;
        float a[8] = {x0.x, x0.y, x0.z, x0.w, y0.x, y0.y, y0.z, y0.w};
        ushort8v hh, ll;
        #pragma unroll
        for (int j = 0; j < 8; j++) {
            float v = a[j] * inv;
            hh[j] = f2bf(v);
            ll[j] = f2bf(v - bf2f(hh[j]));
        }
        g_tf[tfidx(b, th, st, 0, ct, lane)] = hh;
        g_tf[tfidx(b, th, st, 1, ct, lane)] = ll;
    }
    if (two) {  // chunk 1: e0 = 512+8l, s-step = 16 + (l>>2)
        int st = 16 + (l >> 2);
        float a[8] = {x1.x, x1.y, x1.z, x1.w, y1.x, y1.y, y1.z, y1.w};
        ushort8v hh, ll;
        #pragma unroll
        for (int j = 0; j < 8; j++) {
            float v = a[j] * inv;
            hh[j] = f2bf(v);
            ll[j] = f2bf(v - bf2f(hh[j]));
        }
        g_tf[tfidx(b, th, st, 0, ct, lane)] = hh;
        g_tf[tfidx(b, th, st, 1, ct, lane)] = ll;
    }
}

// ---------------- K2 v4: r20 schedule EXACTLY, 64-col quarter tiles -> 4 waves/SIMD ----------------
// Post-mortems v2/v3: both regressions halved waves/SIMD to 1 (MfmaUtil*dur invariant =
// pure scheduling loss). TLP dominates this barrier-per-step structure. v4 keeps r20's
// proven loop verbatim (3-buffer, 2-ahead global_load_lds, A-wait in-order drain,
// lgkmcnt(0)+barrier per step) and only shrinks the col-tile 128->64 (ct quarter of the
// text cols): grid 512->1024 blocks, LDS 24KB/block -> 4 blocks/CU resident = 16 waves/CU
// = 4 waves/SIMD, with 4 independent blocks staggering across barrier stalls. Per-CU pipe
// budgets unchanged (LDS 1536 cyc/step, MFMA 1242). MFMA order per output element and all
// reduction trees unchanged -> bit-identical relevance/invv/diag.
// XCD swizzle: lid = (bid&7)*128 + bid>>3 (bijective, 1024 = 8x128): XCD x owns lids
// x*128.. +127 = 2 full batches (all mt, all 4 quarters) -> g_tf share (1.6MB) L2-resident,
// the 4 quarter-blocks sharing one A-tile are co-XCD (3 of 4 A reads are L2 hits).
__global__ __launch_bounds__(256, 4) void krel(const float* __restrict__ vis) {
    int bid = blockIdx.x;
    int lid = (bid & 7) * 128 + (bid >> 3);   // XCD-grouped logical id
    int b   = lid >> 6;
    int rem = lid & 63;
    int mt  = rem >> 2;                        // 16 row-tiles of 64 rows
    int q   = rem & 3;                         // col quarter (64 text cols)
    int th  = q >> 1;                          // which 128-half of g_tf
    int cb  = (q & 1) * 4;                     // ct base within the half
    int t   = threadIdx.x;
    int w   = t >> 6, l = t & 63;

    __shared__ __align__(16) ushort8v Bfrag[3][2][4][64];  // [buf][hi/lo][ctl][lane], 24KB

    f32x4 acc[4];
    #pragma unroll
    for (int ct = 0; ct < 4; ct++) acc[ct] = (f32x4){0.f, 0.f, 0.f, 0.f};

    // A fragment: row mt*64 + w*16 + (l&15), k-slot (l>>4)*8
    int arow = mt*64 + w*16 + (l & 15);
    const float* Ap = vis + ((size_t)(b*NN + arow))*ND + (l >> 4)*8;

    // B staging: wave w issues chunks c = w*2..w*2+1; c -> (h = c>>2, ctl = c&3)
    const ushort8v* Bbase = g_tf + (size_t)(b*2 + th)*(24*2*8*64);

    #define STAGE(S, P)                                                          \
        {                                                                        \
            _Pragma("unroll")                                                    \
            for (int qq = 0; qq < 2; qq++) {                                     \
                int c   = w*2 + qq;                                              \
                int h   = c >> 2, ctl = c & 3;                                   \
                const ushort8v* gsrc = Bbase + (((size_t)(S)*2 + h)*8 + cb + ctl)*64 + l; \
                __builtin_amdgcn_global_load_lds(                                \
                    (const __attribute__((address_space(1))) void*)gsrc,         \
                    (__attribute__((address_space(3))) void*)&Bfrag[P][h][ctl][0],\
                    16, 0, 0);                                                   \
            }                                                                    \
        }

    // prologue: A regs for step 0; B tiles 0 and 1 into buf 0,1; full drain once
    float4 rax = *(const float4*)(Ap);
    float4 ray = *(const float4*)(Ap + 4);
    STAGE(0, 0);
    STAGE(1, 1);
    __syncthreads();
    float ss = 0.f;

    for (int s = 0; s < 24; s++) {
        int p = s % 3;
        int k0 = s * 32;
        // issue step-(s+2) B loads (2 steps ahead; in flight across the next barrier)
        if (s < 22) STAGE(s + 2, (s + 2) % 3);
        asm volatile("" ::: "memory");   // keep STAGE issued before the A-wait below
        // convert A regs -> hi/lo fragments + sumsq (same order as r20)
        float av[8] = {rax.x, rax.y, rax.z, rax.w, ray.x, ray.y, ray.z, ray.w};
        ushort8v hh, ll;
        #pragma unroll
        for (int j = 0; j < 8; j++) {
            hh[j] = f2bf(av[j]);
            ll[j] = f2bf(av[j] - bf2f(hh[j]));
            ss = fmaf(av[j], av[j], ss);
        }
        short8 ah = *(short8*)&hh;
        short8 al = *(short8*)&ll;
        // prefetch next A regs (issued after this step's STAGE -> next step's A-wait
        // drains STAGE(s+2) via in-order vmcnt; overlaps MFMA below)
        if (s < 23) {
            rax = *(const float4*)(Ap + k0 + 32);
            ray = *(const float4*)(Ap + k0 + 36);
        }
        // MFMA: 4 col-tiles x 4 passes (per-element pass order hh, lh, hl, ll)
        #pragma unroll
        for (int ct = 0; ct < 4; ct++) {
            short8 bh = *(const short8*)&Bfrag[p][0][ct][l];
            short8 bl = *(const short8*)&Bfrag[p][1][ct][l];
            acc[ct] = __builtin_amdgcn_mfma_f32_16x16x32_bf16(ah, bh, acc[ct], 0, 0, 0);
            acc[ct] = __builtin_amdgcn_mfma_f32_16x16x32_bf16(al, bh, acc[ct], 0, 0, 0);
            acc[ct] = __builtin_amdgcn_mfma_f32_16x16x32_bf16(ah, bl, acc[ct], 0, 0, 0);
            acc[ct] = __builtin_amdgcn_mfma_f32_16x16x32_bf16(al, bl, acc[ct], 0, 0, 0);
        }
        if (s < 23) {
            // exec-sync only: staging for step s+1 already drained by this step's
            // A-wait (in-order vmcnt); no vmcnt(0) -> 2-steps-ahead loads stay in flight
            asm volatile("s_waitcnt lgkmcnt(0)" ::: "memory");
            __builtin_amdgcn_s_barrier();
            __builtin_amdgcn_sched_barrier(0);
        }
    }
    #undef STAGE

    // rowmax over this quarter's 64 cols (exact; kfinal maxes the 4 quarters)
    #pragma unroll
    for (int r = 0; r < 4; r++) {
        float m = acc[0][r];
        #pragma unroll
        for (int ct = 1; ct < 4; ct++) m = fmaxf(m, acc[ct][r]);
        #pragma unroll
        for (int off = 1; off <= 8; off <<= 1) m = fmaxf(m, __shfl_xor(m, off));
        if ((l & 15) == 0)
            g_mrawp[(size_t)(b*NN + mt*64 + w*16 + (l >> 4)*4 + r)*4 + q] = m;
    }

    // vis row sumsq -> invv/diag (same combine tree as r20); only q==0 writes
    ss += __shfl_xor(ss, 16);
    ss += __shfl_xor(ss, 32);
    if (q == 0 && l < 16) {
        int row = mt*64 + w*16 + l;
        float nrm = sqrtf(ss);
        float inv = 1.0f / (nrm + 1e-6f);
        g_invv[b*NN + row] = inv;
        float dd = nrm * inv;
        g_diagv[b*NN + row] = dd * dd;
    }
}

// ---------------- K3: prep + reg-sort top-64 + MFMA Gram + single-wave greedy + gather ----------------
__global__ __launch_bounds__(1024) void kfinal(const float* __restrict__ vis,
                                               float* __restrict__ out) {
    int b = blockIdx.x;
    int t = threadIdx.x;
    int w = t >> 6, l = t & 63;

    __shared__ u64   s_key[NN];
    __shared__ float s_reln[NN];
    __shared__ __align__(16) unsigned short Chi[NC][392], Clo[NC][392];  // K-chunk 384 + pad
    __shared__ float s_S[NC*65];
    __shared__ int   s_sel[NSEL], s_srt[NSEL];
    __shared__ float s_mn[16], s_mx[16], s_b2[2];

    // ---- prep: relevance minmax-normalize, di2s0, key (1 elem/thread) ----
    float m0 = g_mrawp[(size_t)(b*NN + t)*4 + 0];
    float m1 = g_mrawp[(size_t)(b*NN + t)*4 + 1];
    float m2 = g_mrawp[(size_t)(b*NN + t)*4 + 2];
    float m3 = g_mrawp[(size_t)(b*NN + t)*4 + 3];
    float iv = g_invv[b*NN + t], dd = g_diagv[b*NN + t];
    float rr = fmaxf(fmaxf(m0, m1), fmaxf(m2, m3)) * iv;
    float lmin = rr, lmax = rr;
    #pragma unroll
    for (int off = 32; off; off >>= 1) {
        lmin = fminf(lmin, __shfl_xor(lmin, off));
        lmax = fmaxf(lmax, __shfl_xor(lmax, off));
    }
    if (l == 0) { s_mn[w] = lmin; s_mx[w] = lmax; }
    __syncthreads();
    if (t == 0) {
        float mn = s_mn[0], mx = s_mx[0];
        #pragma unroll
        for (int qq = 1; qq < 16; qq++) { mn = fminf(mn, s_mn[qq]); mx = fmaxf(mx, s_mx[qq]); }
        s_b2[0] = mn; s_b2[1] = mx;
    }
    __syncthreads();
    float mn = s_b2[0], mx = s_b2[1];
    float den = mx - mn + 1e-6f;
    float rn = (rr - mn + 1e-6f) / den;
    float d0 = rn * rn * dd;
    s_reln[t] = rn;
    u64 kreg = ((u64)(~__float_as_uint(d0)) << 10) | (unsigned)t;

    // ---- per-wave in-register bitonic sort (ascending key = descending d0) ----
    #pragma unroll
    for (int k = 2; k <= 64; k <<= 1) {
        #pragma unroll
        for (int j = k >> 1; j > 0; j >>= 1) {
            u64 part = __shfl_xor(kreg, j);
            bool takeMin = ((l & k) == 0) == ((l & j) == 0);
            kreg = takeMin ? (kreg < part ? kreg : part) : (kreg < part ? part : kreg);
        }
    }
    // ---- symmetric tournament merge: 4 rounds, every wave ends with global top-64 ----
    #pragma unroll
    for (int rnd = 0; rnd < 4; rnd++) {
        int dstp = 8 >> rnd;
        s_key[w*64 + l] = kreg;
        __syncthreads();
        u64 other = s_key[(w ^ dstp)*64 + (63 - l)];
        u64 m = (kreg < other) ? kreg : other;     // 64 smallest of union (bitonic)
        #pragma unroll
        for (int j = 32; j > 0; j >>= 1) {         // ascending clean
            u64 part = __shfl_xor(m, j);
            bool takeMin = ((l & j) == 0);
            m = takeMin ? (m < part ? m : part) : (m < part ? part : m);
        }
        kreg = m;
        __syncthreads();
    }

    // lane l of every wave: l-th best candidate
    int   gid = (int)(kreg & 1023u);
    float d0v = __uint_as_float(~(unsigned)(kreg >> 10));

    // ---- Gram S = vn_c . vn_c^T via bf16x4 MFMA, 2 chunks of K=384 ----
    f32x4 acc = (f32x4){0.f, 0.f, 0.f, 0.f};
    int ar0 = (w >> 2) * 16, bc0 = (w & 3) * 16;
    int cr  = (w << 2) + (l >> 4);                 // candidate row this thread stages
    int sgid = __shfl(gid, cr);
    float sc = g_invv[b*NN + sgid];
    const float* srcrow = vis + (size_t)(b*NN + sgid)*ND + (l & 15)*24;

    for (int c = 0; c < 2; c++) {
        __syncthreads();
        int kb = (l & 15) * 24;
        #pragma unroll
        for (int qq = 0; qq < 3; qq++) {
            float4 x = *(const float4*)(srcrow + c*384 + qq*8);
            float4 y = *(const float4*)(srcrow + c*384 + qq*8 + 4);
            float av[8] = {x.x, x.y, x.z, x.w, y.x, y.y, y.z, y.w};
            ushort8v hh, ll;
            #pragma unroll
            for (int j = 0; j < 8; j++) {
                float vv = av[j] * sc;
                hh[j] = f2bf(vv);
                ll[j] = f2bf(vv - bf2f(hh[j]));
            }
            *(ushort8v*)&Chi[cr][kb + qq*8] = hh;
            *(ushort8v*)&Clo[cr][kb + qq*8] = ll;
        }
        __syncthreads();
        #pragma unroll
        for (int ks = 0; ks < 12; ks++) {
            int ko = ks*32 + (l >> 4)*8;
            short8 ah = *(const short8*)&Chi[ar0 + (l & 15)][ko];
            short8 al = *(const short8*)&Clo[ar0 + (l & 15)][ko];
            short8 bh = *(const short8*)&Chi[bc0 + (l & 15)][ko];
            short8 bl = *(const short8*)&Clo[bc0 + (l & 15)][ko];
            acc = __builtin_amdgcn_mfma_f32_16x16x32_bf16(ah, bh, acc, 0, 0, 0);
            acc = __builtin_amdgcn_mfma_f32_16x16x32_bf16(al, bh, acc, 0, 0, 0);
            acc = __builtin_amdgcn_mfma_f32_16x16x32_bf16(ah, bl, acc, 0, 0, 0);
            acc = __builtin_amdgcn_mfma_f32_16x16x32_bf16(al, bl, acc, 0, 0, 0);
        }
    }
    #pragma unroll
    for (int r = 0; r < 4; r++)
        s_S[(ar0 + (l >> 4)*4 + r)*65 + bc0 + (l & 15)] = acc[r];
    __syncthreads();

    // ---- single-wave greedy: lane = candidate, zero barriers, all state in registers ----
    if (w == 0) {
        float di  = d0v;
        int   gd  = gid;
        float rel = s_reln[gid];
        float ownc[NSEL];
        #pragma unroll
        for (int i = 0; i < NSEL; i++) {
            float vq = fmaxf(di, 1e-12f);
            int   gq = gd;
            int   cq = l;
            #pragma unroll
            for (int off = 32; off; off >>= 1) {
                float vo = __shfl_xor(vq, off);
                int   go = __shfl_xor(gq, off);
                int   co = __shfl_xor(cq, off);
                if (vo > vq || (vo == vq && go < gq)) { vq = vo; gq = go; cq = co; }
            }
            float dj   = __shfl(di, cq);
            float relj = __shfl(rel, cq);
            float denom = sqrtf(fmaxf(dj, 1e-12f)) + 1e-8f;
            if (l == 0) s_sel[i] = gq;

            float cov = 0.f;
            #pragma unroll
            for (int qq = 0; qq < i; qq++)
                cov = fmaf(ownc[qq], __shfl(ownc[qq], cq), cov);

            float sim = s_S[l*65 + cq];
            float kj  = rel * relj * sim;
            float eis = (kj - cov) / denom;
            ownc[i] = eis;
            di = di - eis * eis;
            if (l == cq) di = -__builtin_inff();
        }
    }
    __syncthreads();

    // ---- sort selected indices; wave w gathers output row w ----
    if (t == 0) {
        int vv[16];
        #pragma unroll
        for (int qq = 0; qq < 16; qq++) vv[qq] = s_sel[qq];
        for (int a = 1; a < 16; a++) {
            int key = vv[a]; int p2 = a - 1;
            while (p2 >= 0 && vv[p2] > key) { vv[p2+1] = vv[p2]; p2--; }
            vv[p2+1] = key;
        }
        #pragma unroll
        for (int qq = 0; qq < 16; qq++) s_srt[qq] = vv[qq];
    }
    __syncthreads();
    {
        int idx = s_srt[w];
        const float* src = vis + (size_t)(b*NN + idx)*ND + l*12;
        float*       dst = out + (size_t)(b*NSEL + w)*ND + l*12;
        float4 x = *(const float4*)(src);
        float4 y = *(const float4*)(src + 4);
        float4 z = *(const float4*)(src + 8);
        *(float4*)(dst)     = x;
        *(float4*)(dst + 4) = y;
        *(float4*)(dst + 8) = z;
    }
}

extern "C" void kernel_launch(void* const* d_in, const int* in_sizes, int n_in,
                              void* d_out, int out_size, void* d_ws, size_t ws_size,
                              hipStream_t stream) {
    (void)in_sizes; (void)n_in; (void)d_ws; (void)ws_size; (void)out_size;
    const float* vis = (const float*)d_in[0];
    const float* txt = (const float*)d_in[1];
    float* out = (float*)d_out;

    ktxt  <<<dim3((NB*NT)/4), dim3(256),  0, stream>>>(txt);
    krel  <<<dim3(1024),      dim3(256),  0, stream>>>(vis);
    kfinal<<<dim3(NB),        dim3(1024), 0, stream>>>(vis, out);
}